// Round 9
// baseline (198.680 us; speedup 1.0000x reference)
//
#include <hip/hip_runtime.h>
#include <hip/hip_bf16.h>
#include <math.h>

#define NN 8
#define CH 128
#define HH 36
#define WWI 36
#define PP 1296      // 36*36
#define DD 1156      // 34*34
#define VP 1280      // vb row pitch (shorts) — covers d-tail fragment reads
#define KC 1152      // 128*9
#define QT 81        // q tiles of 16
#define DT 5         // d superblocks of 256 (2x128 flash halves)
#define XPP 1444     // 38*38 padded token grid

typedef __attribute__((ext_vector_type(8))) short short8;
typedef __attribute__((ext_vector_type(4))) float f32x4;
typedef __attribute__((ext_vector_type(8))) _Float16 half8;

__device__ inline unsigned short f2bf(float f) {
    __hip_bfloat16 h = __float2bfloat16(f);
    return __builtin_bit_cast(unsigned short, h);
}
__device__ inline float fast_tanh(float x) {
    float e = __expf(2.f * x);
    return 1.f - 2.f / (e + 1.f);
}
#define MFMA(a, b, c) __builtin_amdgcn_mfma_f32_16x16x32_bf16((a), (b), (c), 0, 0, 0)
#define GLDS(g, l) __builtin_amdgcn_global_load_lds( \
    (const __attribute__((address_space(1))) unsigned int*)(g), \
    (__attribute__((address_space(3))) unsigned int*)(l), 16, 0, 0)

// ---------------------------------------------------------------------------
// setup+proj merged + xp halo-border zeroing (blocks 901..908) — round 8.
// ---------------------------------------------------------------------------
__global__ __launch_bounds__(256)
void k_setup(const float* __restrict__ wq, const float* __restrict__ wk,
             const float* __restrict__ wv, const float* __restrict__ wh,
             const float* __restrict__ wo, const float* __restrict__ wx,
             const float* __restrict__ c0, const float* __restrict__ w_vc,
             const float* __restrict__ b_h,
             unsigned short* __restrict__ wcat, unsigned short* __restrict__ whb,
             unsigned short* __restrict__ wob,
             float* __restrict__ hconst,
             const float* __restrict__ inp, const float* __restrict__ bx,
             unsigned short* __restrict__ xp)
{
    if (blockIdx.x >= 901) {
        const int n = blockIdx.x - 901;
        unsigned short* xpn = xp + (size_t)n * XPP * CH;
        for (int b = threadIdx.x; b < 148 * 16; b += 256) {
            int cell = b >> 4, part = b & 15;
            int y, x;
            if (cell < 38)       { y = 0;              x = cell; }
            else if (cell < 76)  { y = 37;             x = cell - 38; }
            else if (cell < 112) { y = cell - 76 + 1;  x = 0; }
            else                 { y = cell - 112 + 1; x = 37; }
            *(uint4*)&xpn[((size_t)(y * 38 + x)) * CH + part * 8] = make_uint4(0, 0, 0, 0);
        }
        return;
    }
    if (blockIdx.x >= 577) {
        const int t = threadIdx.x;
        const int wave = t >> 6, lane = t & 63;
        const int pid = (blockIdx.x - 577) * 4 + wave;   // 0..1295
        const int n = pid / 162;
        const int rem = pid - n * 162;
        const int by = rem / 81;
        const int qg = rem - by * 81;
        const int quad = lane >> 4, lrow = lane & 15;
        const int p0 = qg * 16;
        const int co0 = by * 64;
        const float* in_n = inp + (size_t)n * CH * PP;
        f32x4 acc[4] = {};

#pragma unroll
        for (int ks = 0; ks < 4; ++ks) {
            union { short8 v; unsigned short u[8]; } a;
            int ci0 = ks * 32 + quad * 8;
#pragma unroll
            for (int j = 0; j < 8; ++j)
                a.u[j] = f2bf(in_n[(size_t)(ci0 + j) * PP + p0 + lrow]);
#pragma unroll
            for (int ni = 0; ni < 4; ++ni) {
                const float* wrow = wx + (size_t)(co0 + ni * 16 + lrow) * CH + ks * 32 + quad * 8;
                float4 f0 = *(const float4*)wrow;
                float4 f1 = *(const float4*)(wrow + 4);
                union { short8 v; unsigned short u[8]; } b;
                b.u[0] = f2bf(f0.x); b.u[1] = f2bf(f0.y);
                b.u[2] = f2bf(f0.z); b.u[3] = f2bf(f0.w);
                b.u[4] = f2bf(f1.x); b.u[5] = f2bf(f1.y);
                b.u[6] = f2bf(f1.z); b.u[7] = f2bf(f1.w);
                acc[ni] = MFMA(a.v, b.v, acc[ni]);
            }
        }
        unsigned short* xn = xp + (size_t)n * XPP * CH;
#pragma unroll
        for (int ni = 0; ni < 4; ++ni) {
            float bv = bx[co0 + ni * 16 + lrow];
#pragma unroll
            for (int r = 0; r < 4; ++r) {
                int p = p0 + quad * 4 + r;
                int off = ((p / 36 + 1) * 38 + (p % 36) + 1) * CH;
                xn[(size_t)off + co0 + ni * 16 + lrow] = f2bf(acc[ni][r] + bv);
            }
        }
        return;
    }
    if (blockIdx.x == 576) {
        __shared__ float c0s[CH];
        __shared__ float part[256];
        __shared__ float vcs[CH];
        const int t = threadIdx.x;
        const int c = t & 127, half = t >> 7;
        if (t < CH) c0s[t] = c0[t];
        __syncthreads();
        {
            const float* row = w_vc + (size_t)c * 1152 + half * 576;
            float s = 0.f;
#pragma unroll 4
            for (int j4 = 0; j4 < 144; ++j4) {
                float4 v = ((const float4*)row)[j4];
                int j = half * 576 + j4 * 4;
                s += v.x * c0s[j / 9] + v.y * c0s[(j + 1) / 9]
                   + v.z * c0s[(j + 2) / 9] + v.w * c0s[(j + 3) / 9];
            }
            part[t] = s;
        }
        __syncthreads();
        if (t < CH) vcs[t] = part[t] + part[t + 128];
        __syncthreads();
        {
            const float* wrow = wh + (size_t)c * 384 + 256 + half * 64;
            float hs = 0.f;
#pragma unroll
            for (int j4 = 0; j4 < 16; ++j4) {
                float4 v = ((const float4*)wrow)[j4];
                int ci = half * 64 + j4 * 4;
                hs += v.x * vcs[ci] + v.y * vcs[ci + 1] + v.z * vcs[ci + 2] + v.w * vcs[ci + 3];
            }
            part[t] = hs;
        }
        __syncthreads();
        if (t < CH) hconst[t] = b_h[t] + part[t] + part[t + 128];
        return;
    }
    int t = blockIdx.x * 256 + threadIdx.x;    // 0..147455
    int co = t / KC;
    int rem = t - co * KC;
    int tap = rem >> 7, ci = rem & 127;
    int iidx = co * KC + ci * 9 + tap;
    wcat[t] = f2bf(wq[iidx]);
    wcat[147456 + t] = f2bf(wk[iidx]);
    wcat[294912 + t] = f2bf(wv[iidx]);
    if (t < 32768) {
        int c2 = t >> 8, k2 = t & 255;
        whb[t] = f2bf(wh[c2 * 384 + k2]);
    }
    if (t < 16384) wob[t] = f2bf(wo[t]);
}

// ---------------------------------------------------------------------------
// fused q/k/v conv — round-8 T3/T4 pipeline (unchanged; measured win).
// ---------------------------------------------------------------------------
__global__ __launch_bounds__(256)
void k_conv(const unsigned short* __restrict__ xp, const unsigned short* __restrict__ wcat,
            unsigned short* __restrict__ qt, unsigned short* __restrict__ kt,
            unsigned short* __restrict__ vb)
{
    __shared__ unsigned short lA[3][2048];   // 3 x 64 rows x 32 shorts
    __shared__ unsigned short lB[3][4096];   // 3 x 128 rows x 32 shorts
    const int t = threadIdx.x;
    const int wave = t >> 6, lane = t & 63;
    const int quad = lane >> 4, lrow = lane & 15;
    const int mode = blockIdx.y;
    const int n = blockIdx.z;
    const int limit = (mode == 0) ? PP : DD;
    const int tile0 = blockIdx.x * 64;
    if (tile0 >= limit) return;
    const unsigned short* xn = xp + (size_t)n * XPP * CH;
    const unsigned short* wb = wcat + (size_t)mode * 128 * KC;

    const int aseg = t & 3;
    int apr, apc;
    {
        int tok = tile0 + (t >> 2); if (tok >= limit) tok = limit - 1;
        int dv = (mode == 0) ? 36 : 34;
        apr = tok / dv; apc = tok - apr * dv;
        if (mode != 0) { apr += 1; apc += 1; }   // mode0: (ky-1)+1 pad cancels
    }
    const unsigned short* wbr0 = wb + (size_t)(wave * 16 + (lane >> 2)) * KC + (lane & 3) * 8;
    const unsigned short* wbr1 = wb + (size_t)(64 + wave * 16 + (lane >> 2)) * KC + (lane & 3) * 8;
    const int ldsA = wave * 512;            // shorts
    const int ldsB0 = wave * 512;
    const int ldsB1 = 2048 + wave * 512;

    auto stage = [&](int ks, int buf) {
        int tap = ks >> 2;
        int ky = tap / 3, kx = tap - ky * 3;
        int ci = (ks & 3) * 32 + aseg * 8;
        const unsigned short* srcA = xn + ((size_t)((apr + ky) * 38 + apc + kx)) * CH + ci;
        int koff = tap * 128 + (ks & 3) * 32;
        GLDS(srcA, &lA[buf][ldsA]);
        GLDS(wbr0 + koff, &lB[buf][ldsB0]);
        GLDS(wbr1 + koff, &lB[buf][ldsB1]);
    };

    f32x4 acc[4][2] = {};
    stage(0, 0);
    stage(1, 1);
    stage(2, 2);

#pragma unroll
    for (int ks = 0; ks < 36; ++ks) {
        if (ks < 34)      asm volatile("s_waitcnt vmcnt(6)" ::: "memory");
        else if (ks == 34) asm volatile("s_waitcnt vmcnt(3)" ::: "memory");
        else               asm volatile("s_waitcnt vmcnt(0)" ::: "memory");
        __builtin_amdgcn_sched_barrier(0);
        __builtin_amdgcn_s_barrier();
        __builtin_amdgcn_sched_barrier(0);
        const int buf = ks % 3;
        short8 b0 = *(const short8*)&lB[buf][(wave * 32 + lrow) * 32 + quad * 8];
        short8 b1 = *(const short8*)&lB[buf][(wave * 32 + 16 + lrow) * 32 + quad * 8];
#pragma unroll
        for (int mi = 0; mi < 4; ++mi) {
            short8 a = *(const short8*)&lA[buf][(mi * 16 + lrow) * 32 + quad * 8];
            acc[mi][0] = MFMA(a, b0, acc[mi][0]);
            acc[mi][1] = MFMA(a, b1, acc[mi][1]);
        }
        __builtin_amdgcn_sched_barrier(0);
        __builtin_amdgcn_s_barrier();
        __builtin_amdgcn_sched_barrier(0);
        if (ks < 33) stage(ks + 3, buf);
    }

    if (mode == 0) {
        unsigned short* qn = qt + (size_t)n * PP * CH;
#pragma unroll
        for (int mi = 0; mi < 4; ++mi)
#pragma unroll
            for (int r = 0; r < 4; ++r) {
                int p = tile0 + mi * 16 + quad * 4 + r;
                if (p < PP)
#pragma unroll
                    for (int ni = 0; ni < 2; ++ni)
                        qn[(size_t)p * CH + (wave * 2 + ni) * 16 + lrow] = f2bf(acc[mi][ni][r]);
            }
    } else if (mode == 1) {
        unsigned short* kn = kt + (size_t)n * DD * CH;
#pragma unroll
        for (int mi = 0; mi < 4; ++mi)
#pragma unroll
            for (int r = 0; r < 4; ++r) {
                int d = tile0 + mi * 16 + quad * 4 + r;
                if (d < DD)
#pragma unroll
                    for (int ni = 0; ni < 2; ++ni)
                        kn[(size_t)d * CH + (wave * 2 + ni) * 16 + lrow] = f2bf(acc[mi][ni][r]);
            }
    } else {
        unsigned short* vn = vb + (size_t)n * CH * VP;
#pragma unroll
        for (int mi = 0; mi < 4; ++mi)
#pragma unroll
            for (int r = 0; r < 4; ++r) {
                int d = tile0 + mi * 16 + quad * 4 + r;
                if (d < DD)
#pragma unroll
                    for (int ni = 0; ni < 2; ++ni)
                        vn[(size_t)((wave * 2 + ni) * 16 + lrow) * VP + d] = f2bf(acc[mi][ni][r]);
            }
    }
}

// ---------------------------------------------------------------------------
// partial attention — T3/T4 pipeline: K/V chunks staged via global_load_lds
// (width 16, 2 issues/thread/chunk) into a 2-deep linear ring; counted
// vmcnt(2) before each consume (next chunk's loads stay in flight across
// both barriers), vmcnt(0) only at the last chunk. Softmax overlaps the
// in-flight V loads. LDS 33.8 KB -> 4 blocks/CU. Math identical to R6.
// ---------------------------------------------------------------------------
__global__ __launch_bounds__(256)
void k_attn(const unsigned short* __restrict__ qt, const unsigned short* __restrict__ kt,
            const unsigned short* __restrict__ vb, _Float16* __restrict__ po,
            float* __restrict__ pm, float* __restrict__ pl)
{
    __shared__ unsigned short ring[2][4096];      // 2 x 8 KB GLDS ring
    __shared__ unsigned short lp[4][16 * 136];    // per-wave P transpose
    const int t = threadIdx.x;
    const int wave = t >> 6, lane = t & 63;
    const int quad = lane >> 4, lrow = lane & 15;
    const int qg = blockIdx.x;
    const int dt = blockIdx.y;                    // 0..4
    const int n = blockIdx.z;
    const int qti = qg * 4 + wave;                // may be >= QT (tail)
    const int d0 = dt * 256;
    const unsigned short* qn = qt + (size_t)n * PP * CH;
    const unsigned short* kn = kt + (size_t)n * DD * CH;
    const unsigned short* vn = vb + (size_t)n * CH * VP;

    const int lrow4 = lane >> 2;      // 0..15
    const int lseg = lane & 3;

    // chunk c in 0..15: h = c>>3, type = (c>>2)&1 (0=K,1=V), k = c&3, buf = c&1
    auto stage = [&](int c) {
        const int h = c >> 3, k = c & 3, isV = (c >> 2) & 1;
        const int dbase = d0 + h * 128;
        const int buf = c & 1;
#pragma unroll
        for (int j = 0; j < 2; ++j) {
            const int rowc = j * 64 + wave * 16 + lrow4;
            const unsigned short* src;
            if (!isV) {
                int row = dbase + rowc; if (row >= DD) row = DD - 1;
                src = kn + (size_t)row * CH + k * 32 + lseg * 8;
            } else {
                src = vn + (size_t)rowc * VP + dbase + k * 32 + lseg * 8;
            }
            GLDS(src, &ring[buf][j * 2048 + wave * 512]);
        }
    };

    short8 qa[4];
    {
        int qrow = qti * 16 + lrow; if (qrow >= PP) qrow = PP - 1;
#pragma unroll
        for (int ks = 0; ks < 4; ++ks)
            qa[ks] = *(const short8*)&qn[(size_t)qrow * CH + ks * 32 + quad * 8];
    }

    f32x4 o[8] = {};
    float mx[4] = {-1e30f, -1e30f, -1e30f, -1e30f};
    float rs[4] = {0.f, 0.f, 0.f, 0.f};

    stage(0);
    stage(1);

#pragma unroll
    for (int h = 0; h < 2; ++h) {
        const int dbase = d0 + h * 128;
        f32x4 s[8] = {};

        // ---- S = Q.K^T : 4 K-chunks, pipelined ----
#pragma unroll
        for (int k = 0; k < 4; ++k) {
            const int c = h * 8 + k;
            asm volatile("s_waitcnt vmcnt(2)" ::: "memory");
            __builtin_amdgcn_sched_barrier(0);
            __builtin_amdgcn_s_barrier();
            __builtin_amdgcn_sched_barrier(0);
            const int buf = c & 1;
#pragma unroll
            for (int ni = 0; ni < 8; ++ni) {
                short8 b = *(const short8*)&ring[buf][(ni * 16 + lrow) * 32 + quad * 8];
                s[ni] = MFMA(qa[k], b, s[ni]);
            }
            __builtin_amdgcn_sched_barrier(0);
            __builtin_amdgcn_s_barrier();
            __builtin_amdgcn_sched_barrier(0);
            stage(c + 2);
        }

        // ---- tail mask + online-softmax combine (overlaps V loads) ----
#pragma unroll
        for (int ni = 0; ni < 8; ++ni)
            if (dbase + ni * 16 + lrow >= DD)
#pragma unroll
                for (int r = 0; r < 4; ++r) s[ni][r] = -1e30f;

        float hm[4] = {-1e30f, -1e30f, -1e30f, -1e30f};
#pragma unroll
        for (int ni = 0; ni < 8; ++ni)
#pragma unroll
            for (int r = 0; r < 4; ++r) hm[r] = fmaxf(hm[r], s[ni][r]);
#pragma unroll
        for (int off = 1; off < 16; off <<= 1)
#pragma unroll
            for (int r = 0; r < 4; ++r) hm[r] = fmaxf(hm[r], __shfl_xor(hm[r], off, 64));

        float m[4], sc[4];
#pragma unroll
        for (int r = 0; r < 4; ++r) {
            m[r] = fmaxf(mx[r], hm[r]);
            sc[r] = __expf(mx[r] - m[r]);   // h=0: exp(-1e30 - finite) = 0
        }

        float hs[4] = {0.f, 0.f, 0.f, 0.f};
#pragma unroll
        for (int ni = 0; ni < 8; ++ni)
#pragma unroll
            for (int r = 0; r < 4; ++r) {
                float e = __expf(s[ni][r] - m[r]);
                s[ni][r] = e;
                hs[r] += e;
            }
#pragma unroll
        for (int off = 1; off < 16; off <<= 1)
#pragma unroll
            for (int r = 0; r < 4; ++r) hs[r] += __shfl_xor(hs[r], off, 64);
#pragma unroll
        for (int r = 0; r < 4; ++r) {
            rs[r] = rs[r] * sc[r] + hs[r];
            mx[r] = m[r];
        }
#pragma unroll
        for (int ni = 0; ni < 8; ++ni)
#pragma unroll
            for (int r = 0; r < 4; ++r) o[ni][r] *= sc[r];

        // P -> wave-private LDS (C-layout -> A-layout transpose)
#pragma unroll
        for (int ni = 0; ni < 8; ++ni)
#pragma unroll
            for (int r = 0; r < 4; ++r)
                lp[wave][(quad * 4 + r) * 136 + ni * 16 + lrow] = f2bf(s[ni][r]);

        // ---- O += P.V : 4 V-chunks, pipelined ----
#pragma unroll
        for (int k = 0; k < 4; ++k) {
            const int c = h * 8 + 4 + k;
            if (c == 15) asm volatile("s_waitcnt vmcnt(0)" ::: "memory");
            else         asm volatile("s_waitcnt vmcnt(2)" ::: "memory");
            __builtin_amdgcn_sched_barrier(0);
            __builtin_amdgcn_s_barrier();
            __builtin_amdgcn_sched_barrier(0);
            const int buf = c & 1;
            short8 pa = *(const short8*)&lp[wave][lrow * 136 + k * 32 + quad * 8];
#pragma unroll
            for (int ni = 0; ni < 8; ++ni) {
                short8 b = *(const short8*)&ring[buf][(ni * 16 + lrow) * 32 + quad * 8];
                o[ni] = MFMA(pa, b, o[ni]);
            }
            __builtin_amdgcn_sched_barrier(0);
            __builtin_amdgcn_s_barrier();
            __builtin_amdgcn_sched_barrier(0);
            if (c + 2 < 16) stage(c + 2);
        }
    }

    if (qti < QT) {
        const int base = (n * QT + qti) * DT + dt;
        _Float16* pob = po + (size_t)base * 2048;
#pragma unroll
        for (int ni = 0; ni < 8; ++ni)
#pragma unroll
            for (int r = 0; r < 4; ++r)
                pob[(quad * 4 + r) * 128 + ni * 16 + lrow] = (_Float16)o[ni][r];
        if (lrow == 0)
#pragma unroll
            for (int r = 0; r < 4; ++r) {
                pm[base * 16 + quad * 4 + r] = mx[r];
                pl[base * 16 + quad * 4 + r] = rs[r];
            }
    }
}

// ---------------------------------------------------------------------------
// fused attention-reduce + h + out — round-8 version (padded xp reads).
// ---------------------------------------------------------------------------
__global__ __launch_bounds__(256)
void k_ahout(const _Float16* __restrict__ po, const float* __restrict__ pm,
             const float* __restrict__ pl, const unsigned short* __restrict__ xp,
             const unsigned short* __restrict__ whb, const float* __restrict__ hconst,
             const unsigned short* __restrict__ wob, const float* __restrict__ bo,
             float* __restrict__ out)
{
    __shared__ float sm[80], ssc[80], smg[16], sli[16];
    __shared__ unsigned short la0[16 * 136];
    __shared__ unsigned short lh[16 * 136];
    const int qti = blockIdx.x;
    const int n = blockIdx.y;
    const int base = (n * QT + qti) * DT;
    const int t = threadIdx.x;

    // ---- phase 1: merge the 5 d-superblock partials -> la0[16q x 128c] ----
    if (t < 80) sm[t] = pm[base * 16 + t];
    __syncthreads();
    if (t < 16) {
        float mg = -1e30f;
#pragma unroll
        for (int dt = 0; dt < DT; ++dt) mg = fmaxf(mg, sm[dt * 16 + t]);
        float ls = 0.f;
#pragma unroll
        for (int dt = 0; dt < DT; ++dt) ls += __expf(sm[dt * 16 + t] - mg) * pl[base * 16 + dt * 16 + t];
        smg[t] = mg; sli[t] = 1.f / ls;
    }
    __syncthreads();
    if (t < 80) ssc[t] = __expf(sm[t] - smg[t & 15]);
    __syncthreads();
    {
        const int row = t >> 4;              // (t*8)>>7
        const int c0 = (t & 15) * 8;
        float acc[8] = {};
#pragma unroll
        for (int dt = 0; dt < DT; ++dt) {
            half8 v = *(const half8*)&po[(size_t)(base + dt) * 2048 + t * 8];
            float scv = ssc[dt * 16 + row];
#pragma unroll
            for (int j = 0; j < 8; ++j) acc[j] += scv * (float)v[j];
        }
        float inv = sli[row];
#pragma unroll
        for (int j = 0; j < 8; ++j)
            la0[row * 136 + c0 + j] = f2bf(acc[j] * inv);
    }
    __syncthreads();

    // ---- phase 2: h = tanh(whb.[x;a0]+hconst) -> lh -> out = wob.h+b_o ----
    const int wave = t >> 6, lane = t & 63;
    const int quad = lane >> 4, lrow = lane & 15;
    const int p0 = qti * 16;
    const unsigned short* x0 = xp + (size_t)n * XPP * CH;
    const int ptok = p0 + lrow;
    const int xoff = ((ptok / 36 + 1) * 38 + (ptok % 36) + 1) * CH;

    f32x4 acc1[2] = {};
#pragma unroll
    for (int ks = 0; ks < 8; ++ks) {
        int col = (ks & 3) * 32 + quad * 8;
        short8 a;
        if (ks < 4) a = *(const short8*)&x0[(size_t)xoff + col];
        else        a = *(const short8*)&la0[lrow * 136 + col];
#pragma unroll
        for (int j = 0; j < 2; ++j) {
            int ni = wave * 2 + j;
            short8 b = *(const short8*)&whb[(size_t)(ni * 16 + lrow) * 256 + ks * 32 + quad * 8];
            acc1[j] = MFMA(a, b, acc1[j]);
        }
    }
#pragma unroll
    for (int j = 0; j < 2; ++j) {
        int ni = wave * 2 + j;
        float hc = hconst[ni * 16 + lrow];
#pragma unroll
        for (int r = 0; r < 4; ++r)
            lh[(quad * 4 + r) * 136 + ni * 16 + lrow] = f2bf(fast_tanh(acc1[j][r] + hc));
    }
    __syncthreads();

    f32x4 acc2[2] = {};
#pragma unroll
    for (int ks = 0; ks < 4; ++ks) {
        short8 a = *(const short8*)&lh[lrow * 136 + ks * 32 + quad * 8];
#pragma unroll
        for (int j = 0; j < 2; ++j) {
            int ni = wave * 2 + j;
            short8 b = *(const short8*)&wob[(size_t)(ni * 16 + lrow) * CH + ks * 32 + quad * 8];
            acc2[j] = MFMA(a, b, acc2[j]);
        }
    }
#pragma unroll
    for (int j = 0; j < 2; ++j) {
        int ni = wave * 2 + j;
        float bv = bo[ni * 16 + lrow];
#pragma unroll
        for (int r = 0; r < 4; ++r)
            out[((size_t)(n * CH + ni * 16 + lrow)) * PP + p0 + quad * 4 + r] = acc2[j][r] + bv;
    }
}

// ---------------------------------------------------------------------------
extern "C" void kernel_launch(void* const* d_in, const int* in_sizes, int n_in,
                              void* d_out, int out_size, void* d_ws, size_t ws_size,
                              hipStream_t stream)
{
    const float* inp  = (const float*)d_in[0];
    const float* c0   = (const float*)d_in[1];
    const float* w_x  = (const float*)d_in[2];
    const float* b_x  = (const float*)d_in[3];
    const float* w_qx = (const float*)d_in[4];
    const float* w_kx = (const float*)d_in[6];
    const float* w_vx = (const float*)d_in[8];
    const float* w_vc = (const float*)d_in[9];
    const float* w_h  = (const float*)d_in[14];
    const float* b_h  = (const float*)d_in[15];
    const float* w_o  = (const float*)d_in[16];
    const float* b_o  = (const float*)d_in[17];
    float* out = (float*)d_out;

    char* w = (char*)d_ws;
    unsigned short* xp   = (unsigned short*)(w);             // 2,957,312 (38*38*128*2*8)
    unsigned short* qt   = (unsigned short*)(w + 2957312);   // 2,654,208
    unsigned short* kt   = (unsigned short*)(w + 5611520);   // 2,367,488
    unsigned short* vb   = (unsigned short*)(w + 7979008);   // 2,621,440
    unsigned short* wcat = (unsigned short*)(w + 10600448);  // 884,736
    unsigned short* whb  = (unsigned short*)(w + 11485184);  // 65,536
    unsigned short* wob  = (unsigned short*)(w + 11550720);  // 32,768
    float* hconst        = (float*)(w + 11583488);           // 512
    float* pm            = (float*)(w + 11616256);           // 207,360
    float* pl            = (float*)(w + 11824128);           // 207,360
    _Float16* po         = (_Float16*)(w + 12031488);        // 13,271,040

    // setup 0..575 | hconst 576 | proj 577..900 | xp-border zero 901..908
    hipLaunchKernelGGL(k_setup, dim3(909), dim3(256), 0, stream,
                       w_qx, w_kx, w_vx, w_h, w_o, w_x, c0, w_vc, b_h,
                       wcat, whb, wob, hconst, inp, b_x, xp);

    hipLaunchKernelGGL(k_conv, dim3(21, 3, NN), dim3(256), 0, stream, xp, wcat, qt, kt, vb);

    hipLaunchKernelGGL(k_attn, dim3(21, DT, NN), dim3(256), 0, stream, qt, kt, vb, po, pm, pl);

    hipLaunchKernelGGL(k_ahout, dim3(QT, NN), dim3(256), 0, stream,
                       po, pm, pl, xp, whb, hconst, wob, b_o, out);
}

// Round 10
// 182.705 us; speedup vs baseline: 1.0874x; 1.0874x over previous
//
#include <hip/hip_runtime.h>
#include <hip/hip_bf16.h>
#include <math.h>

#define NN 8
#define CH 128
#define HH 36
#define WWI 36
#define PP 1296      // 36*36
#define DD 1156      // 34*34
#define VP 1280      // vb row pitch (shorts) — covers d-tail fragment reads
#define KC 1152      // 128*9
#define QT 81        // q tiles of 16
#define DT 5         // d superblocks of 256 (2x128 flash halves)
#define XPP 1444     // 38*38 padded token grid

typedef __attribute__((ext_vector_type(8))) short short8;
typedef __attribute__((ext_vector_type(4))) float f32x4;
typedef __attribute__((ext_vector_type(8))) _Float16 half8;

__device__ inline unsigned short f2bf(float f) {
    __hip_bfloat16 h = __float2bfloat16(f);
    return __builtin_bit_cast(unsigned short, h);
}
__device__ inline float fast_tanh(float x) {
    float e = __expf(2.f * x);
    return 1.f - 2.f / (e + 1.f);
}
#define MFMA(a, b, c) __builtin_amdgcn_mfma_f32_16x16x32_bf16((a), (b), (c), 0, 0, 0)
#define GLDS(g, l) __builtin_amdgcn_global_load_lds( \
    (const __attribute__((address_space(1))) unsigned int*)(g), \
    (__attribute__((address_space(3))) unsigned int*)(l), 16, 0, 0)

// ---------------------------------------------------------------------------
// setup+proj merged + xp halo-border zeroing (blocks 901..908) — round 8.
// ---------------------------------------------------------------------------
__global__ __launch_bounds__(256)
void k_setup(const float* __restrict__ wq, const float* __restrict__ wk,
             const float* __restrict__ wv, const float* __restrict__ wh,
             const float* __restrict__ wo, const float* __restrict__ wx,
             const float* __restrict__ c0, const float* __restrict__ w_vc,
             const float* __restrict__ b_h,
             unsigned short* __restrict__ wcat, unsigned short* __restrict__ whb,
             unsigned short* __restrict__ wob,
             float* __restrict__ hconst,
             const float* __restrict__ inp, const float* __restrict__ bx,
             unsigned short* __restrict__ xp)
{
    if (blockIdx.x >= 901) {
        const int n = blockIdx.x - 901;
        unsigned short* xpn = xp + (size_t)n * XPP * CH;
        for (int b = threadIdx.x; b < 148 * 16; b += 256) {
            int cell = b >> 4, part = b & 15;
            int y, x;
            if (cell < 38)       { y = 0;              x = cell; }
            else if (cell < 76)  { y = 37;             x = cell - 38; }
            else if (cell < 112) { y = cell - 76 + 1;  x = 0; }
            else                 { y = cell - 112 + 1; x = 37; }
            *(uint4*)&xpn[((size_t)(y * 38 + x)) * CH + part * 8] = make_uint4(0, 0, 0, 0);
        }
        return;
    }
    if (blockIdx.x >= 577) {
        const int t = threadIdx.x;
        const int wave = t >> 6, lane = t & 63;
        const int pid = (blockIdx.x - 577) * 4 + wave;   // 0..1295
        const int n = pid / 162;
        const int rem = pid - n * 162;
        const int by = rem / 81;
        const int qg = rem - by * 81;
        const int quad = lane >> 4, lrow = lane & 15;
        const int p0 = qg * 16;
        const int co0 = by * 64;
        const float* in_n = inp + (size_t)n * CH * PP;
        f32x4 acc[4] = {};

#pragma unroll
        for (int ks = 0; ks < 4; ++ks) {
            union { short8 v; unsigned short u[8]; } a;
            int ci0 = ks * 32 + quad * 8;
#pragma unroll
            for (int j = 0; j < 8; ++j)
                a.u[j] = f2bf(in_n[(size_t)(ci0 + j) * PP + p0 + lrow]);
#pragma unroll
            for (int ni = 0; ni < 4; ++ni) {
                const float* wrow = wx + (size_t)(co0 + ni * 16 + lrow) * CH + ks * 32 + quad * 8;
                float4 f0 = *(const float4*)wrow;
                float4 f1 = *(const float4*)(wrow + 4);
                union { short8 v; unsigned short u[8]; } b;
                b.u[0] = f2bf(f0.x); b.u[1] = f2bf(f0.y);
                b.u[2] = f2bf(f0.z); b.u[3] = f2bf(f0.w);
                b.u[4] = f2bf(f1.x); b.u[5] = f2bf(f1.y);
                b.u[6] = f2bf(f1.z); b.u[7] = f2bf(f1.w);
                acc[ni] = MFMA(a.v, b.v, acc[ni]);
            }
        }
        unsigned short* xn = xp + (size_t)n * XPP * CH;
#pragma unroll
        for (int ni = 0; ni < 4; ++ni) {
            float bv = bx[co0 + ni * 16 + lrow];
#pragma unroll
            for (int r = 0; r < 4; ++r) {
                int p = p0 + quad * 4 + r;
                int off = ((p / 36 + 1) * 38 + (p % 36) + 1) * CH;
                xn[(size_t)off + co0 + ni * 16 + lrow] = f2bf(acc[ni][r] + bv);
            }
        }
        return;
    }
    if (blockIdx.x == 576) {
        __shared__ float c0s[CH];
        __shared__ float part[256];
        __shared__ float vcs[CH];
        const int t = threadIdx.x;
        const int c = t & 127, half = t >> 7;
        if (t < CH) c0s[t] = c0[t];
        __syncthreads();
        {
            const float* row = w_vc + (size_t)c * 1152 + half * 576;
            float s = 0.f;
#pragma unroll 4
            for (int j4 = 0; j4 < 144; ++j4) {
                float4 v = ((const float4*)row)[j4];
                int j = half * 576 + j4 * 4;
                s += v.x * c0s[j / 9] + v.y * c0s[(j + 1) / 9]
                   + v.z * c0s[(j + 2) / 9] + v.w * c0s[(j + 3) / 9];
            }
            part[t] = s;
        }
        __syncthreads();
        if (t < CH) vcs[t] = part[t] + part[t + 128];
        __syncthreads();
        {
            const float* wrow = wh + (size_t)c * 384 + 256 + half * 64;
            float hs = 0.f;
#pragma unroll
            for (int j4 = 0; j4 < 16; ++j4) {
                float4 v = ((const float4*)wrow)[j4];
                int ci = half * 64 + j4 * 4;
                hs += v.x * vcs[ci] + v.y * vcs[ci + 1] + v.z * vcs[ci + 2] + v.w * vcs[ci + 3];
            }
            part[t] = hs;
        }
        __syncthreads();
        if (t < CH) hconst[t] = b_h[t] + part[t] + part[t + 128];
        return;
    }
    int t = blockIdx.x * 256 + threadIdx.x;    // 0..147455
    int co = t / KC;
    int rem = t - co * KC;
    int tap = rem >> 7, ci = rem & 127;
    int iidx = co * KC + ci * 9 + tap;
    wcat[t] = f2bf(wq[iidx]);
    wcat[147456 + t] = f2bf(wk[iidx]);
    wcat[294912 + t] = f2bf(wv[iidx]);
    if (t < 32768) {
        int c2 = t >> 8, k2 = t & 255;
        whb[t] = f2bf(wh[c2 * 384 + k2]);
    }
    if (t < 16384) wob[t] = f2bf(wo[t]);
}

// ---------------------------------------------------------------------------
// fused q/k/v conv — round-8 T3/T4 pipeline + T5 setprio around the MFMA
// cluster (phase-split structure = T5's prerequisite).
// ---------------------------------------------------------------------------
__global__ __launch_bounds__(256)
void k_conv(const unsigned short* __restrict__ xp, const unsigned short* __restrict__ wcat,
            unsigned short* __restrict__ qt, unsigned short* __restrict__ kt,
            unsigned short* __restrict__ vb)
{
    __shared__ unsigned short lA[3][2048];   // 3 x 64 rows x 32 shorts
    __shared__ unsigned short lB[3][4096];   // 3 x 128 rows x 32 shorts
    const int t = threadIdx.x;
    const int wave = t >> 6, lane = t & 63;
    const int quad = lane >> 4, lrow = lane & 15;
    const int mode = blockIdx.y;
    const int n = blockIdx.z;
    const int limit = (mode == 0) ? PP : DD;
    const int tile0 = blockIdx.x * 64;
    if (tile0 >= limit) return;
    const unsigned short* xn = xp + (size_t)n * XPP * CH;
    const unsigned short* wb = wcat + (size_t)mode * 128 * KC;

    const int aseg = t & 3;
    int apr, apc;
    {
        int tok = tile0 + (t >> 2); if (tok >= limit) tok = limit - 1;
        int dv = (mode == 0) ? 36 : 34;
        apr = tok / dv; apc = tok - apr * dv;
        if (mode != 0) { apr += 1; apc += 1; }   // mode0: (ky-1)+1 pad cancels
    }
    const unsigned short* wbr0 = wb + (size_t)(wave * 16 + (lane >> 2)) * KC + (lane & 3) * 8;
    const unsigned short* wbr1 = wb + (size_t)(64 + wave * 16 + (lane >> 2)) * KC + (lane & 3) * 8;
    const int ldsA = wave * 512;            // shorts
    const int ldsB0 = wave * 512;
    const int ldsB1 = 2048 + wave * 512;

    auto stage = [&](int ks, int buf) {
        int tap = ks >> 2;
        int ky = tap / 3, kx = tap - ky * 3;
        int ci = (ks & 3) * 32 + aseg * 8;
        const unsigned short* srcA = xn + ((size_t)((apr + ky) * 38 + apc + kx)) * CH + ci;
        int koff = tap * 128 + (ks & 3) * 32;
        GLDS(srcA, &lA[buf][ldsA]);
        GLDS(wbr0 + koff, &lB[buf][ldsB0]);
        GLDS(wbr1 + koff, &lB[buf][ldsB1]);
    };

    f32x4 acc[4][2] = {};
    stage(0, 0);
    stage(1, 1);
    stage(2, 2);

#pragma unroll
    for (int ks = 0; ks < 36; ++ks) {
        if (ks < 34)      asm volatile("s_waitcnt vmcnt(6)" ::: "memory");
        else if (ks == 34) asm volatile("s_waitcnt vmcnt(3)" ::: "memory");
        else               asm volatile("s_waitcnt vmcnt(0)" ::: "memory");
        __builtin_amdgcn_sched_barrier(0);
        __builtin_amdgcn_s_barrier();
        __builtin_amdgcn_sched_barrier(0);
        const int buf = ks % 3;
        short8 b0 = *(const short8*)&lB[buf][(wave * 32 + lrow) * 32 + quad * 8];
        short8 b1 = *(const short8*)&lB[buf][(wave * 32 + 16 + lrow) * 32 + quad * 8];
        __builtin_amdgcn_s_setprio(1);
#pragma unroll
        for (int mi = 0; mi < 4; ++mi) {
            short8 a = *(const short8*)&lA[buf][(mi * 16 + lrow) * 32 + quad * 8];
            acc[mi][0] = MFMA(a, b0, acc[mi][0]);
            acc[mi][1] = MFMA(a, b1, acc[mi][1]);
        }
        __builtin_amdgcn_s_setprio(0);
        __builtin_amdgcn_sched_barrier(0);
        __builtin_amdgcn_s_barrier();
        __builtin_amdgcn_sched_barrier(0);
        if (ks < 33) stage(ks + 3, buf);
    }

    if (mode == 0) {
        unsigned short* qn = qt + (size_t)n * PP * CH;
#pragma unroll
        for (int mi = 0; mi < 4; ++mi)
#pragma unroll
            for (int r = 0; r < 4; ++r) {
                int p = tile0 + mi * 16 + quad * 4 + r;
                if (p < PP)
#pragma unroll
                    for (int ni = 0; ni < 2; ++ni)
                        qn[(size_t)p * CH + (wave * 2 + ni) * 16 + lrow] = f2bf(acc[mi][ni][r]);
            }
    } else if (mode == 1) {
        unsigned short* kn = kt + (size_t)n * DD * CH;
#pragma unroll
        for (int mi = 0; mi < 4; ++mi)
#pragma unroll
            for (int r = 0; r < 4; ++r) {
                int d = tile0 + mi * 16 + quad * 4 + r;
                if (d < DD)
#pragma unroll
                    for (int ni = 0; ni < 2; ++ni)
                        kn[(size_t)d * CH + (wave * 2 + ni) * 16 + lrow] = f2bf(acc[mi][ni][r]);
            }
    } else {
        unsigned short* vn = vb + (size_t)n * CH * VP;
#pragma unroll
        for (int mi = 0; mi < 4; ++mi)
#pragma unroll
            for (int r = 0; r < 4; ++r) {
                int d = tile0 + mi * 16 + quad * 4 + r;
                if (d < DD)
#pragma unroll
                    for (int ni = 0; ni < 2; ++ni)
                        vn[(size_t)((wave * 2 + ni) * 16 + lrow) * VP + d] = f2bf(acc[mi][ni][r]);
            }
    }
}

// ---------------------------------------------------------------------------
// partial attention — ROUND-6 reg-staged version (reverted from R9's GLDS
// ring, which regressed: short phases made the doubled barrier count
// dominate). Best measured structure for this kernel.
// ---------------------------------------------------------------------------
__global__ __launch_bounds__(256)
void k_attn(const unsigned short* __restrict__ qt, const unsigned short* __restrict__ kt,
            const unsigned short* __restrict__ vb, _Float16* __restrict__ po,
            float* __restrict__ pm, float* __restrict__ pl)
{
    __shared__ unsigned short lS[2][128 * 40];    // 2 x 10240 B chunk staging
    __shared__ unsigned short lp[4][16 * 136];    // per-wave P transpose
    const int t = threadIdx.x;
    const int wave = t >> 6, lane = t & 63;
    const int quad = lane >> 4, lrow = lane & 15;
    const int qg = blockIdx.x;
    const int dt = blockIdx.y;                    // 0..4
    const int n = blockIdx.z;
    const int qti = qg * 4 + wave;                // may be >= QT (tail)
    const int d0 = dt * 256;
    const unsigned short* qn = qt + (size_t)n * PP * CH;
    const unsigned short* kn = kt + (size_t)n * DD * CH;
    const unsigned short* vn = vb + (size_t)n * CH * VP;

    const int arow = t >> 2, aseg8 = (t & 3) * 8;
    const int lo0 = arow * 40 + aseg8;
    const int lo1 = (arow + 64) * 40 + aseg8;

    short8 qa[4];
    {
        int qrow = qti * 16 + lrow; if (qrow >= PP) qrow = PP - 1;
#pragma unroll
        for (int ks = 0; ks < 4; ++ks)
            qa[ks] = *(const short8*)&qn[(size_t)qrow * CH + ks * 32 + quad * 8];
    }

    f32x4 o[8] = {};
    float mx[4] = {-1e30f, -1e30f, -1e30f, -1e30f};
    float rs[4] = {0.f, 0.f, 0.f, 0.f};

#pragma unroll
    for (int h = 0; h < 2; ++h) {
        const int dbase = d0 + h * 128;
        int kr0 = dbase + arow;      if (kr0 >= DD) kr0 = DD - 1;
        int kr1 = dbase + arow + 64; if (kr1 >= DD) kr1 = DD - 1;
        const unsigned short* kp0 = kn + (size_t)kr0 * CH + aseg8;
        const unsigned short* kp1 = kn + (size_t)kr1 * CH + aseg8;
        const unsigned short* vp0 = vn + (size_t)arow * VP + dbase + aseg8;
        const unsigned short* vp1 = vn + (size_t)(arow + 64) * VP + dbase + aseg8;

        // ---- S = Q.K^T for this half, chunked over c, double-buffered ----
        f32x4 s[8] = {};
        uint4 r0 = *(const uint4*)kp0;
        uint4 r1 = *(const uint4*)kp1;
        *(uint4*)&lS[0][lo0] = r0;
        *(uint4*)&lS[0][lo1] = r1;
        __syncthreads();
#pragma unroll
        for (int ks = 0; ks < 4; ++ks) {
            const int buf = ks & 1;
            if (ks < 3) {
                r0 = *(const uint4*)(kp0 + (ks + 1) * 32);
                r1 = *(const uint4*)(kp1 + (ks + 1) * 32);
            }
#pragma unroll
            for (int ni = 0; ni < 8; ++ni) {
                short8 b = *(const short8*)&lS[buf][(ni * 16 + lrow) * 40 + quad * 8];
                s[ni] = MFMA(qa[ks], b, s[ni]);
            }
            if (ks < 3) {
                *(uint4*)&lS[buf ^ 1][lo0] = r0;
                *(uint4*)&lS[buf ^ 1][lo1] = r1;
            }
            __syncthreads();
        }

        // ---- tail mask + online-softmax combine (per wave) ----
#pragma unroll
        for (int ni = 0; ni < 8; ++ni)
            if (dbase + ni * 16 + lrow >= DD)
#pragma unroll
                for (int r = 0; r < 4; ++r) s[ni][r] = -1e30f;

        float hm[4] = {-1e30f, -1e30f, -1e30f, -1e30f};
#pragma unroll
        for (int ni = 0; ni < 8; ++ni)
#pragma unroll
            for (int r = 0; r < 4; ++r) hm[r] = fmaxf(hm[r], s[ni][r]);
#pragma unroll
        for (int off = 1; off < 16; off <<= 1)
#pragma unroll
            for (int r = 0; r < 4; ++r) hm[r] = fmaxf(hm[r], __shfl_xor(hm[r], off, 64));

        float m[4], sc[4];
#pragma unroll
        for (int r = 0; r < 4; ++r) {
            m[r] = fmaxf(mx[r], hm[r]);
            sc[r] = __expf(mx[r] - m[r]);   // h=0: exp(-1e30 - finite) = 0
        }

        float hs[4] = {0.f, 0.f, 0.f, 0.f};
#pragma unroll
        for (int ni = 0; ni < 8; ++ni)
#pragma unroll
            for (int r = 0; r < 4; ++r) {
                float e = __expf(s[ni][r] - m[r]);
                s[ni][r] = e;
                hs[r] += e;
            }
#pragma unroll
        for (int off = 1; off < 16; off <<= 1)
#pragma unroll
            for (int r = 0; r < 4; ++r) hs[r] += __shfl_xor(hs[r], off, 64);
#pragma unroll
        for (int r = 0; r < 4; ++r) {
            rs[r] = rs[r] * sc[r] + hs[r];
            mx[r] = m[r];
        }
        // rescale running O before accumulating this half's PV
#pragma unroll
        for (int ni = 0; ni < 8; ++ni)
#pragma unroll
            for (int r = 0; r < 4; ++r) o[ni][r] *= sc[r];

        // P -> wave-private LDS (C-layout -> A-layout transpose)
#pragma unroll
        for (int ni = 0; ni < 8; ++ni)
#pragma unroll
            for (int r = 0; r < 4; ++r)
                lp[wave][(quad * 4 + r) * 136 + ni * 16 + lrow] = f2bf(s[ni][r]);

        // ---- O += P.V for this half, chunked over d ----
        r0 = *(const uint4*)vp0;
        r1 = *(const uint4*)vp1;
        *(uint4*)&lS[0][lo0] = r0;
        *(uint4*)&lS[0][lo1] = r1;
        __syncthreads();
#pragma unroll
        for (int ks = 0; ks < 4; ++ks) {
            const int buf = ks & 1;
            if (ks < 3) {
                r0 = *(const uint4*)(vp0 + (ks + 1) * 32);
                r1 = *(const uint4*)(vp1 + (ks + 1) * 32);
            }
            short8 pa = *(const short8*)&lp[wave][lrow * 136 + ks * 32 + quad * 8];
#pragma unroll
            for (int ni = 0; ni < 8; ++ni) {
                short8 b = *(const short8*)&lS[buf][(ni * 16 + lrow) * 40 + quad * 8];
                o[ni] = MFMA(pa, b, o[ni]);
            }
            if (ks < 3) {
                *(uint4*)&lS[buf ^ 1][lo0] = r0;
                *(uint4*)&lS[buf ^ 1][lo1] = r1;
            }
            __syncthreads();
        }
    }

    if (qti < QT) {
        const int base = (n * QT + qti) * DT + dt;
        _Float16* pob = po + (size_t)base * 2048;
#pragma unroll
        for (int ni = 0; ni < 8; ++ni)
#pragma unroll
            for (int r = 0; r < 4; ++r)
                pob[(quad * 4 + r) * 128 + ni * 16 + lrow] = (_Float16)o[ni][r];
        if (lrow == 0)
#pragma unroll
            for (int r = 0; r < 4; ++r) {
                pm[base * 16 + quad * 4 + r] = mx[r];
                pl[base * 16 + quad * 4 + r] = rs[r];
            }
    }
}

// ---------------------------------------------------------------------------
// fused attention-reduce + h + out — round-8 version (padded xp reads).
// ---------------------------------------------------------------------------
__global__ __launch_bounds__(256)
void k_ahout(const _Float16* __restrict__ po, const float* __restrict__ pm,
             const float* __restrict__ pl, const unsigned short* __restrict__ xp,
             const unsigned short* __restrict__ whb, const float* __restrict__ hconst,
             const unsigned short* __restrict__ wob, const float* __restrict__ bo,
             float* __restrict__ out)
{
    __shared__ float sm[80], ssc[80], smg[16], sli[16];
    __shared__ unsigned short la0[16 * 136];
    __shared__ unsigned short lh[16 * 136];
    const int qti = blockIdx.x;
    const int n = blockIdx.y;
    const int base = (n * QT + qti) * DT;
    const int t = threadIdx.x;

    // ---- phase 1: merge the 5 d-superblock partials -> la0[16q x 128c] ----
    if (t < 80) sm[t] = pm[base * 16 + t];
    __syncthreads();
    if (t < 16) {
        float mg = -1e30f;
#pragma unroll
        for (int dt = 0; dt < DT; ++dt) mg = fmaxf(mg, sm[dt * 16 + t]);
        float ls = 0.f;
#pragma unroll
        for (int dt = 0; dt < DT; ++dt) ls += __expf(sm[dt * 16 + t] - mg) * pl[base * 16 + dt * 16 + t];
        smg[t] = mg; sli[t] = 1.f / ls;
    }
    __syncthreads();
    if (t < 80) ssc[t] = __expf(sm[t] - smg[t & 15]);
    __syncthreads();
    {
        const int row = t >> 4;              // (t*8)>>7
        const int c0 = (t & 15) * 8;
        float acc[8] = {};
#pragma unroll
        for (int dt = 0; dt < DT; ++dt) {
            half8 v = *(const half8*)&po[(size_t)(base + dt) * 2048 + t * 8];
            float scv = ssc[dt * 16 + row];
#pragma unroll
            for (int j = 0; j < 8; ++j) acc[j] += scv * (float)v[j];
        }
        float inv = sli[row];
#pragma unroll
        for (int j = 0; j < 8; ++j)
            la0[row * 136 + c0 + j] = f2bf(acc[j] * inv);
    }
    __syncthreads();

    // ---- phase 2: h = tanh(whb.[x;a0]+hconst) -> lh -> out = wob.h+b_o ----
    const int wave = t >> 6, lane = t & 63;
    const int quad = lane >> 4, lrow = lane & 15;
    const int p0 = qti * 16;
    const unsigned short* x0 = xp + (size_t)n * XPP * CH;
    const int ptok = p0 + lrow;
    const int xoff = ((ptok / 36 + 1) * 38 + (ptok % 36) + 1) * CH;

    f32x4 acc1[2] = {};
#pragma unroll
    for (int ks = 0; ks < 8; ++ks) {
        int col = (ks & 3) * 32 + quad * 8;
        short8 a;
        if (ks < 4) a = *(const short8*)&x0[(size_t)xoff + col];
        else        a = *(const short8*)&la0[lrow * 136 + col];
#pragma unroll
        for (int j = 0; j < 2; ++j) {
            int ni = wave * 2 + j;
            short8 b = *(const short8*)&whb[(size_t)(ni * 16 + lrow) * 256 + ks * 32 + quad * 8];
            acc1[j] = MFMA(a, b, acc1[j]);
        }
    }
#pragma unroll
    for (int j = 0; j < 2; ++j) {
        int ni = wave * 2 + j;
        float hc = hconst[ni * 16 + lrow];
#pragma unroll
        for (int r = 0; r < 4; ++r)
            lh[(quad * 4 + r) * 136 + ni * 16 + lrow] = f2bf(fast_tanh(acc1[j][r] + hc));
    }
    __syncthreads();

    f32x4 acc2[2] = {};
#pragma unroll
    for (int ks = 0; ks < 4; ++ks) {
        short8 a = *(const short8*)&lh[lrow * 136 + ks * 32 + quad * 8];
#pragma unroll
        for (int j = 0; j < 2; ++j) {
            int ni = wave * 2 + j;
            short8 b = *(const short8*)&wob[(size_t)(ni * 16 + lrow) * CH + ks * 32 + quad * 8];
            acc2[j] = MFMA(a, b, acc2[j]);
        }
    }
#pragma unroll
    for (int j = 0; j < 2; ++j) {
        int ni = wave * 2 + j;
        float bv = bo[ni * 16 + lrow];
#pragma unroll
        for (int r = 0; r < 4; ++r)
            out[((size_t)(n * CH + ni * 16 + lrow)) * PP + p0 + quad * 4 + r] = acc2[j][r] + bv;
    }
}

// ---------------------------------------------------------------------------
extern "C" void kernel_launch(void* const* d_in, const int* in_sizes, int n_in,
                              void* d_out, int out_size, void* d_ws, size_t ws_size,
                              hipStream_t stream)
{
    const float* inp  = (const float*)d_in[0];
    const float* c0   = (const float*)d_in[1];
    const float* w_x  = (const float*)d_in[2];
    const float* b_x  = (const float*)d_in[3];
    const float* w_qx = (const float*)d_in[4];
    const float* w_kx = (const float*)d_in[6];
    const float* w_vx = (const float*)d_in[8];
    const float* w_vc = (const float*)d_in[9];
    const float* w_h  = (const float*)d_in[14];
    const float* b_h  = (const float*)d_in[15];
    const float* w_o  = (const float*)d_in[16];
    const float* b_o  = (const float*)d_in[17];
    float* out = (float*)d_out;

    char* w = (char*)d_ws;
    unsigned short* xp   = (unsigned short*)(w);             // 2,957,312 (38*38*128*2*8)
    unsigned short* qt   = (unsigned short*)(w + 2957312);   // 2,654,208
    unsigned short* kt   = (unsigned short*)(w + 5611520);   // 2,367,488
    unsigned short* vb   = (unsigned short*)(w + 7979008);   // 2,621,440
    unsigned short* wcat = (unsigned short*)(w + 10600448);  // 884,736
    unsigned short* whb  = (unsigned short*)(w + 11485184);  // 65,536
    unsigned short* wob  = (unsigned short*)(w + 11550720);  // 32,768
    float* hconst        = (float*)(w + 11583488);           // 512
    float* pm            = (float*)(w + 11616256);           // 207,360
    float* pl            = (float*)(w + 11824128);           // 207,360
    _Float16* po         = (_Float16*)(w + 12031488);        // 13,271,040

    // setup 0..575 | hconst 576 | proj 577..900 | xp-border zero 901..908
    hipLaunchKernelGGL(k_setup, dim3(909), dim3(256), 0, stream,
                       w_qx, w_kx, w_vx, w_h, w_o, w_x, c0, w_vc, b_h,
                       wcat, whb, wob, hconst, inp, b_x, xp);

    hipLaunchKernelGGL(k_conv, dim3(21, 3, NN), dim3(256), 0, stream, xp, wcat, qt, kt, vb);

    hipLaunchKernelGGL(k_attn, dim3(21, DT, NN), dim3(256), 0, stream, qt, kt, vb, po, pm, pl);

    hipLaunchKernelGGL(k_ahout, dim3(QT, NN), dim3(256), 0, stream,
                       po, pm, pl, xp, whb, hconst, wob, b_o, out);
}